// Round 3
// baseline (242.085 us; speedup 1.0000x reference)
//
#include <hip/hip_runtime.h>
#include <math.h>

// Per-position head-vs-head attention (Hilbert perm cancels; see R0 notes).
// R4: depth-2 software pipeline, global_load_lds, counted vmcnt, 0 barriers.
// History: R1 84us (16 waves/CU, bursty); R2 FAILED (nt-stores: 2.4x write
// amplification -- but its reg-pipeline raised achieved B/s by ~20%, the only
// positive signal so far); R3 NEUTRAL (occupancy 2x -> no change: not pure-TLP
// bound; queueing equilibrium, per-wave memory duty cycle is the lever).
// Now: each wave owns 4 tasks (task = one 8-head group of one position);
// while computing task t from LDS buffer A, task t+1 streams into buffer B
// via global_load_lds (width 16, linear lane x 16B dest -- m97/m104) and q
// into regs. Consumption gated by counted s_waitcnt vmcnt(N) (T4):
// steady-state N=8 = 6 stage-ops + 2 stores younger than the target stage.
// sched_barrier(0) after each asm wait per rule #18 (hipcc hoists ds-dependent
// ops past inline-asm waitcnt otherwise).

#define HEADS 16
#define DIM 64
#define GH 8                       // heads per group (task = one group)
#define GFLOATS (GH * DIM)         // 512 floats = 2KB: one group, one tensor
#define BUFF (2 * GFLOATS)         // 1024 floats: k+v for one task
#define WSLICE (2 * BUFF)          // 2048 floats: double buffer = 8KB/wave
#define WPB 4                      // waves per block -> 32KB block, 5 blocks/CU

typedef float f32x4 __attribute__((ext_vector_type(4)));

// global -> LDS direct, 16B/lane; dest = wave-uniform base + lane*16 (m104).
#define GLD16(gsrc, ldst_base) \
  __builtin_amdgcn_global_load_lds( \
      (const __attribute__((address_space(1))) unsigned int*)(gsrc), \
      (__attribute__((address_space(3))) unsigned int*)(ldst_base), 16, 0, 0)

template <int N>
__device__ __forceinline__ void wait_vmcnt() {
  asm volatile("s_waitcnt vmcnt(%0)" ::"n"(N) : "memory");
  __builtin_amdgcn_sched_barrier(0);   // rule #18
}

// Issue one task's stage: 4x gld_lds (k,v -> buf) + 2x q loads (regs). 6 VMEM.
__device__ __forceinline__ void stage(const float* __restrict__ q,
                                      const float* __restrict__ k,
                                      const float* __restrict__ v,
                                      long long gbase, int lane,
                                      float* buf, f32x4& q0, f32x4& q1) {
  GLD16(k + gbase + lane * 4,       buf);          // k rows 0..3
  GLD16(k + gbase + 256 + lane * 4, buf + 256);    // k rows 4..7
  GLD16(v + gbase + lane * 4,       buf + 512);    // v rows 0..3
  GLD16(v + gbase + 256 + lane * 4, buf + 768);    // v rows 4..7
  const int i = lane >> 3, s = lane & 7;
  const float* qp = q + gbase + i * DIM + s * 8;
  q0 = *(const f32x4*)(qp + 0);
  q1 = *(const f32x4*)(qp + 4);
}

// 8x8 head-attention for one group; lane(i,s): head i, dim-chunk s (8 floats).
__device__ __forceinline__ void compute(const float* buf, int lane,
                                        f32x4 q0, f32x4 q1,
                                        f32x4& o0, f32x4& o1) {
  const int s = lane & 7;
  const float* kk = buf;
  const float* vv = buf + GFLOATS;

  float sc[8];
#pragma unroll
  for (int j = 0; j < 8; ++j) {        // partial dots over this lane's 8 dims
    const float* kr = kk + j * DIM + s * 8;
    f32x4 p = q0 * *(const f32x4*)(kr + 0) + q1 * *(const f32x4*)(kr + 4);
    sc[j] = p.x + p.y + p.z + p.w;
  }
#pragma unroll
  for (int j = 0; j < 8; ++j) {        // complete over the 8 s-lanes
    sc[j] += __shfl_xor(sc[j], 1);
    sc[j] += __shfl_xor(sc[j], 2);
    sc[j] += __shfl_xor(sc[j], 4);
    sc[j] *= 0.125f;                   // HEAD_DIM^-0.5
  }
  float m = sc[0];
#pragma unroll
  for (int j = 1; j < 8; ++j) m = fmaxf(m, sc[j]);
  float at[8];
  float sum = 0.f;
#pragma unroll
  for (int j = 0; j < 8; ++j) { at[j] = __expf(sc[j] - m); sum += at[j]; }
  const float inv = 1.f / sum;

  o0 = (f32x4){0.f, 0.f, 0.f, 0.f};
  o1 = o0;
#pragma unroll
  for (int j = 0; j < 8; ++j) {
    const float a = at[j] * inv;
    const float* vr = vv + j * DIM + s * 8;
    o0 += a * *(const f32x4*)(vr + 0);
    o1 += a * *(const f32x4*)(vr + 4);
  }
}

__device__ __forceinline__ long long task_base(long long t) {
  return (t >> 1) * (long long)(HEADS * DIM) + (t & 1) * (long long)GFLOATS;
}

__global__ void __launch_bounds__(256, 5) hilbert_attn_kernel(
    const float* __restrict__ q,
    const float* __restrict__ k,
    const float* __restrict__ v,
    float* __restrict__ out,
    int npos)
{
  __shared__ float lds[WPB * WSLICE];       // 32,768 B -> 5 blocks/CU
  const int wave = threadIdx.x >> 6;
  const int lane = threadIdx.x & 63;
  const long long S  = (long long)gridDim.x * WPB;   // task stride
  const long long NT = 2LL * npos;                   // 2 group-tasks/position

  long long t = (long long)blockIdx.x * WPB + wave;
  if (t >= NT) return;                       // wave-uniform; no barriers below

  float* buf0 = lds + wave * WSLICE;         // wave-private double buffer
  float* buf1 = buf0 + BUFF;
  const int i = lane >> 3, s = lane & 7;
  const long long lofs = (long long)(i * DIM + s * 8);

  f32x4 qA0, qA1, qB0, qB1, o0, o1;

  stage(q, k, v, task_base(t), lane, buf0, qA0, qA1);
  if (t + S < NT) {
    stage(q, k, v, task_base(t + S), lane, buf1, qB0, qB1);
    wait_vmcnt<6>();                         // buf0 ready (6 younger ops)
  } else {
    wait_vmcnt<0>();
  }

  for (;;) {
    // ---- phase A: compute task t from buf0/qA; prefetch t+2S into buf0.
    compute(buf0, lane, qA0, qA1, o0, o1);
    {
      asm volatile("s_waitcnt lgkmcnt(0)" ::: "memory");  // buf0 reads done
      __builtin_amdgcn_sched_barrier(0);                  // before overwrite
      const bool pf = (t + 2 * S < NT);
      if (pf) stage(q, k, v, task_base(t + 2 * S), lane, buf0, qA0, qA1);
      float* op = out + task_base(t) + lofs;
      *(f32x4*)(op + 0) = o0;
      *(f32x4*)(op + 4) = o1;
      t += S;
      if (t >= NT) return;
      if (pf) wait_vmcnt<8>(); else wait_vmcnt<2>();      // buf1 ready
    }
    // ---- phase B: mirror with buf1/qB.
    compute(buf1, lane, qB0, qB1, o0, o1);
    {
      asm volatile("s_waitcnt lgkmcnt(0)" ::: "memory");
      __builtin_amdgcn_sched_barrier(0);
      const bool pf = (t + 2 * S < NT);
      if (pf) stage(q, k, v, task_base(t + 2 * S), lane, buf1, qB0, qB1);
      float* op = out + task_base(t) + lofs;
      *(f32x4*)(op + 0) = o0;
      *(f32x4*)(op + 4) = o1;
      t += S;
      if (t >= NT) return;
      if (pf) wait_vmcnt<8>(); else wait_vmcnt<2>();      // buf0 ready
    }
  }
}

extern "C" void kernel_launch(void* const* d_in, const int* in_sizes, int n_in,
                              void* d_out, int out_size, void* d_ws, size_t ws_size,
                              hipStream_t stream) {
  const float* q = (const float*)d_in[0];
  const float* k = (const float*)d_in[1];
  const float* v = (const float*)d_in[2];
  float* out = (float*)d_out;

  const int npos = in_sizes[0] / (HEADS * DIM);   // B*S = 16384
  const long long ntasks = 2LL * npos;            // 32768
  // 4 tasks per wave, depth-2 pipeline; 2048 blocks (5/CU resident, drained
  // continuously -- no residency cliff).
  const long long nwaves = (ntasks + 3) / 4;
  const int blocks = (int)((nwaves + WPB - 1) / WPB);
  hilbert_attn_kernel<<<blocks, WPB * 64, 0, stream>>>(q, k, v, out, npos);
}

// Round 4
// 211.518 us; speedup vs baseline: 1.1445x; 1.1445x over previous
//
#include <hip/hip_runtime.h>
#include <math.h>

// Per-position head-vs-head attention (Hilbert perm cancels; see R0 notes).
// R5: all-coalesced R3. History: R1 85us (burst, exact traffic); R2 FAILED
// (persistent reg-pipeline + nt stores: write RMW amplification); R3 83.5us
// (2x occupancy -> NEUTRAL: not TLP-bound; queueing equilibrium); R4 FAILED
// (persistent gld_lds pipeline: FETCH+50%, WRITE+165% -- 2nd independent
// trial where the persistent grid-stride loop amplified traffic. Rule:
// one-shot burst waves only).
// R5 theory: Little's law on R3 implies ~5us effective load latency ->
// queues saturated at ~3.2 TB/s CU-side while HBM is at 2.0/6.3 -> the
// limiter is REQUEST rate, not bytes. R3's q-loads and stores are
// half-coverage (16B per lane at 32B stride): every line requested twice
// with half sectors -> 96 line-requests/task for 64 lines of bytes. Fix:
// stage q through LDS like k/v, and bounce the output through LDS, so every
// global instruction is a fully-contiguous full-coverage 1KB block ->
// 64 requests/task, all full-sector. Compute topology identical to R3.
// Zero barriers (wave-private LDS), no persistent loop, no global_load_lds.

#define HEADS 16
#define DIM 64
#define GH 8                       // heads per group (task = one group)
#define GFLOATS (GH * DIM)         // 512 floats = 2KB: one group, one tensor
#define WSLICE (3 * GFLOATS)       // k + v + q(/out-bounce) = 6KB per wave
#define WPB 4                      // waves per block -> 24KB block, 6 blocks/CU

typedef float f32x4 __attribute__((ext_vector_type(4)));

__global__ void __launch_bounds__(256, 6) hilbert_attn_kernel(
    const float* __restrict__ q,
    const float* __restrict__ k,
    const float* __restrict__ v,
    float* __restrict__ out,
    int npos)
{
    __shared__ float lds[WPB * WSLICE];   // 24,576 B -> 6 blocks/CU (24 w/CU)
    const int wave = threadIdx.x >> 6;
    const int lane = threadIdx.x & 63;

    const long long w   = (long long)blockIdx.x * WPB + wave; // global wave id
    const long long pos = w >> 1;
    const int       grp = (int)(w & 1);
    if (pos >= npos) return;              // wave-uniform; no barriers below

    float* kk = lds + wave * WSLICE;      // wave-private: no __syncthreads
    float* vv = kk + GFLOATS;
    float* qq = vv + GFLOATS;             // later reused as the out-bounce

    // Group g of position p is a contiguous 512-float block in [H][D] layout.
    const long long gbase = pos * (HEADS * DIM) + (long long)grp * GFLOATS;

    // ---- Stage k, v, q: every instruction is 1KB contiguous, full-coverage
    // (lane*16B). 6 loads + 6 ds_write_b128, canonical conflict-free pattern.
    {
        const int fo0 = lane * 4;
        const int fo1 = 256 + lane * 4;
        f32x4 a0 = *(const f32x4*)(k + gbase + fo0);
        f32x4 a1 = *(const f32x4*)(k + gbase + fo1);
        f32x4 b0 = *(const f32x4*)(v + gbase + fo0);
        f32x4 b1 = *(const f32x4*)(v + gbase + fo1);
        f32x4 c0 = *(const f32x4*)(q + gbase + fo0);
        f32x4 c1 = *(const f32x4*)(q + gbase + fo1);
        *(f32x4*)(kk + fo0) = a0;  *(f32x4*)(kk + fo1) = a1;
        *(f32x4*)(vv + fo0) = b0;  *(f32x4*)(vv + fo1) = b1;
        *(f32x4*)(qq + fo0) = c0;  *(f32x4*)(qq + fo1) = c1;
    }
    // Compiler inserts vm/lgkm waits; same-wave DS ops are pipe-ordered.

    const int i = lane >> 3;              // head within group (0..7)
    const int s = lane & 7;               // 8-float dim chunk (0..7)

    // ---- q sub-row from LDS (2-way bank aliasing at worst: free, m136).
    const float* qp = qq + i * DIM + s * 8;
    f32x4 q0 = *(const f32x4*)(qp + 0);
    f32x4 q1 = *(const f32x4*)(qp + 4);

    // ---- Phase A: partial scores over this lane's 8 dims, all 8 j.
    float sc[8];
#pragma unroll
    for (int j = 0; j < 8; ++j) {
        const float* kr = kk + j * DIM + s * 8;
        f32x4 p = q0 * *(const f32x4*)(kr + 0)
                + q1 * *(const f32x4*)(kr + 4);
        sc[j] = p.x + p.y + p.z + p.w;
    }
    // Complete dots across the 8 s-lanes (lane = i*8+s; bits 0..2 are s).
#pragma unroll
    for (int j = 0; j < 8; ++j) {
        sc[j] += __shfl_xor(sc[j], 1);
        sc[j] += __shfl_xor(sc[j], 2);
        sc[j] += __shfl_xor(sc[j], 4);
        sc[j] *= 0.125f;                  // HEAD_DIM^-0.5
    }

    // ---- Softmax fully in-lane (every s-lane holds the full score row).
    float m = sc[0];
#pragma unroll
    for (int j = 1; j < 8; ++j) m = fmaxf(m, sc[j]);
    float at[8];
    float sum = 0.f;
#pragma unroll
    for (int j = 0; j < 8; ++j) { at[j] = __expf(sc[j] - m); sum += at[j]; }
    const float inv = 1.f / sum;
#pragma unroll
    for (int j = 0; j < 8; ++j) at[j] *= inv;

    // ---- Phase B: out[i][s*8..s*8+8) = sum_j at[j] * v[j][chunk s]
    f32x4 o0 = {0.f, 0.f, 0.f, 0.f};
    f32x4 o1 = o0;
#pragma unroll
    for (int j = 0; j < 8; ++j) {
        const float a = at[j];
        const float* vr = vv + j * DIM + s * 8;
        o0 += a * *(const f32x4*)(vr + 0);
        o1 += a * *(const f32x4*)(vr + 4);
    }

    // ---- Bounce output through LDS (qq slot; q already consumed) so the
    // global stores are 2 fully-contiguous full-coverage 1KB instructions.
    // Same-wave DS ordering + compiler alias analysis on `lds` keep this safe.
    float* ob = qq;
    float* op = ob + i * DIM + s * 8;
    *(f32x4*)(op + 0) = o0;
    *(f32x4*)(op + 4) = o1;
    f32x4 r0 = *(const f32x4*)(ob + lane * 4);
    f32x4 r1 = *(const f32x4*)(ob + 256 + lane * 4);
    *(f32x4*)(out + gbase + lane * 4)       = r0;
    *(f32x4*)(out + gbase + 256 + lane * 4) = r1;
}

extern "C" void kernel_launch(void* const* d_in, const int* in_sizes, int n_in,
                              void* d_out, int out_size, void* d_ws, size_t ws_size,
                              hipStream_t stream) {
    const float* q = (const float*)d_in[0];
    const float* k = (const float*)d_in[1];
    const float* v = (const float*)d_in[2];
    float* out = (float*)d_out;

    const int npos = in_sizes[0] / (HEADS * DIM);   // B*S = 16384
    const long long nwaves = 2LL * npos;            // 2 group-tasks/position
    const int blocks = (int)((nwaves + WPB - 1) / WPB);   // 8192
    hilbert_attn_kernel<<<blocks, WPB * 64, 0, stream>>>(q, k, v, out, npos);
}